// Round 11
// baseline (165.751 us; speedup 1.0000x reference)
//
#include <hip/hip_runtime.h>
#include <stdint.h>

typedef short s16x8 __attribute__((ext_vector_type(8)));
typedef float f32x4 __attribute__((ext_vector_type(4)));

#define IN_F   256
#define OUT_F  256
#define BATCH  16384
#define NB     31
#define KONE   8192
#define KTOT   8448

typedef const __attribute__((address_space(1))) void* as1cvp;
typedef __attribute__((address_space(3))) void* as3vp;

__device__ __forceinline__ unsigned short f2bf(float f) {
    unsigned u = __float_as_uint(f);
    u += 0x7FFFu + ((u >> 16) & 1u);   // RNE
    return (unsigned short)(u >> 16);
}

// ---------------- kernel 1: fused prep --------------------------------------
// blk 0..255  : column min/max partials -> pmn/pmx[256][256]
// blk 256..511: Haar-synthesize Wb row o = blk-256
// blk 512..767: zero out (z-split atomics accumulate into it)
__global__ __launch_bounds__(256) void prep1(
    const float* __restrict__ x, const float* __restrict__ bw,
    const float* __restrict__ sw, const float* __restrict__ sc,
    float* __restrict__ pmn, float* __restrict__ pmx,
    unsigned short* __restrict__ Wb, float* __restrict__ outz) {
    const int blk = blockIdx.x, t = threadIdx.x;
    if (blk < 256) {
        const int b0 = blk * 64;
        float mn = 3.4e38f, mx = -3.4e38f;
        for (int r = 0; r < 64; ++r) {
            float v = x[(size_t)(b0 + r) * IN_F + t];
            mn = fminf(mn, v);
            mx = fmaxf(mx, v);
        }
        pmn[blk * 256 + t] = mn;
        pmx[blk * 256 + t] = mx;
    } else if (blk < 512) {
        const int o = blk - 256, i = t;
        const float s = sc[o * IN_F + i];
        const float* swp = sw + (size_t)(o * IN_F + i) * NB;
        float w[NB];
#pragma unroll
        for (int k = 0; k < NB; ++k) w[k] = swp[k];
        unsigned short* dst = Wb + (size_t)o * KTOT + i * 32;
#pragma unroll
        for (int q = 0; q < 4; ++q) {
            union { s16x8 v; unsigned short s8[8]; } pk;
#pragma unroll
            for (int e = 0; e < 8; ++e) {
                int j = q * 8 + e;
                float acc = 0.f;
#pragma unroll
                for (int l = 0; l < 5; ++l) {
                    int kk = (1 << l) - 1 + (j >> (5 - l));
                    acc += (((j >> (4 - l)) & 1) ? -w[kk] : w[kk]);
                }
                pk.s8[e] = f2bf(acc * s);
            }
            *(s16x8*)(dst + q * 8) = pk.v;
        }
        Wb[(size_t)o * KTOT + KONE + i] = f2bf(bw[o * IN_F + i]);
    } else {
        float4 z; z.x = z.y = z.z = z.w = 0.f;
        float4* oz = (float4*)outz + (size_t)(blk - 512) * 4096;
#pragma unroll
        for (int r = 0; r < 16; ++r) oz[t + r * 256] = z;
    }
}

// ---------------- kernel 2: reduce + transposed leaves (verbatim R9) --------
__global__ __launch_bounds__(256) void leaf2t(
    const float* __restrict__ x, const float* __restrict__ pmn,
    const float* __restrict__ pmx, unsigned char* __restrict__ lt) {
    __shared__ unsigned char lsh[256 * 68];    // [i][r], stride 68 (odd dword)
    __shared__ float xminsh[IN_F], rdnsh[IN_F];
    const int t = threadIdx.x;
    {
        float mn0 = 3.4e38f, mn1 = 3.4e38f, mx0 = -3.4e38f, mx1 = -3.4e38f;
#pragma unroll 8
        for (int b = 0; b < 256; b += 2) {
            mn0 = fminf(mn0, pmn[(size_t)b * 256 + t]);
            mn1 = fminf(mn1, pmn[(size_t)(b + 1) * 256 + t]);
            mx0 = fmaxf(mx0, pmx[(size_t)b * 256 + t]);
            mx1 = fmaxf(mx1, pmx[(size_t)(b + 1) * 256 + t]);
        }
        float mn = fminf(mn0, mn1), mx = fmaxf(mx0, mx1);
        xminsh[t] = mn;
        rdnsh[t] = 1.0f / (mx - mn + 1e-8f);   // verified chain: rcp-mult
    }
    __syncthreads();
    const float xmn = xminsh[t], rdn = rdnsh[t];
    const int b0 = blockIdx.x * 64;
    for (int r = 0; r < 64; ++r) {
        float v = x[(size_t)(b0 + r) * IN_F + t];
        float xn = (v - xmn) * rdn;
        int l = (int)(xn * 32.0f);
        lsh[t * 68 + r] = (l >= 0 && l < 32) ? (unsigned char)l : (unsigned char)255;
    }
    __syncthreads();
    const int lane = t & 63, w = t >> 6;
    const unsigned* lshU = (const unsigned*)lsh;
#pragma unroll
    for (int ib = 0; ib < 16; ++ib) {
        int i = ib * 16 + w * 4 + (lane >> 4);
        unsigned val = lshU[i * 17 + (lane & 15)];
        *(unsigned*)(lt + (size_t)i * BATCH + b0 + (lane & 15) * 4) = val;
    }
}

// ---------------- kernel 3: M128xN128 block, M64xN64 wave tiles -------------
// R10 failed on ONE bug: the A-tile zero prologue was dropped (one-hot scheme
// requires a clean tile; garbage LDS -> absmax 101). Fixed here: zero Ash +
// lgkmcnt(0) drain before the prologue; first BAR_A publishes the zeros,
// BAR_B's lgkmcnt(0)+barrier publishes one-hot writes before each MFMA read.
// Everything else verbatim R10 (schedule invariants re-audited: FIFO 10->5
// steady state, peel waits 5/4/4/4/0, ring-3 slot induction, WAR via BAR_A).
// Rationale (R9 diagnosis): LDS-READ-BW-bound at M32xN64 (16 FLOP/LDS-byte,
// 4.4GB/52TB/s = 85us = measured). M64xN64 wave tile -> 32 FLOP/B. 4 waves
// (2x2), tile M128xN128, z-split x2 + atomicAdd, 2 blocks/CU = 2 waves/SIMD.
__global__ __launch_bounds__(256, 2) void gemm_kan(
    const float* __restrict__ x,
    const unsigned short* __restrict__ Wb,
    const unsigned char* __restrict__ lt,
    float* __restrict__ out)
{
    __shared__ unsigned short Ash[128 * 64];       // 16KB, XOR-swizzled chunks
    __shared__ unsigned short Bsh[3 * 128 * 64];   // 48KB, ring-3 (16KB slots)

    const int t     = threadIdx.x;     // 0..255
    const int lane  = t & 63;
    const int wv    = t >> 6;          // 0..3
    const int wm    = wv >> 1, wn = wv & 1;
    const int mtile = blockIdx.x;      // 0..127
    const int ntile = blockIdx.y;      // 0..1
    const int zz    = blockIdx.z;      // 0..1
    const int kbeg  = zz ? 66 : 0;
    const int kend1 = zz ? 128 : 66;   // one-hot end (dense 128..131 in z=1)

    const int rr = lane & 15, kq = lane >> 4;
    const int mbase = mtile * 128;

    // ---- THE R10 FIX: zero the A tile (one-hot invariant needs clean LDS) ----
    {
        uint4 z; z.x = z.y = z.z = z.w = 0u;
        uint4* a4 = (uint4*)Ash;                   // 1024 uint4 = 16KB
#pragma unroll
        for (int r = 0; r < 4; ++r) a4[t + r * 256] = z;
    }
    asm volatile("s_waitcnt lgkmcnt(0)" ::: "memory");   // own zeros drained

    // B glds source: wave wv stages N-rows 32wv..+31 of the ntile*128 panel;
    // chunk pre-swizzled by (lane&7)^(lane>>3) -> linear LDS dest law.
    const unsigned char* bbase = (const unsigned char*)(Wb
        + (size_t)(ntile * 128 + wv * 32 + (lane >> 3)) * KTOT
        + (((lane & 7) ^ (lane >> 3)) << 3));

    // one-hot identities: 256 threads -> (row am 0..127, feature ag 0..1)
    const int am = t >> 1;
    const int ag = t & 1;
    int ps = -1;

    f32x4 acc[4][4] = {};

#define FENCE() asm volatile("" ::: "memory")

#define STAGE(KB, SLOT)                                                        \
    {                                                                          \
        const unsigned char* _s = bbase + (size_t)(KB) * 128;                  \
        unsigned short* _d = Bsh + (SLOT) * 8192 + wv * 2048;                  \
        _Pragma("unroll")                                                      \
        for (int q = 0; q < 4; ++q)                                            \
            __builtin_amdgcn_global_load_lds(                                  \
                (as1cvp)(_s + (size_t)q * 8 * KTOT * 2),                       \
                (as3vp)(uint32_t)(uintptr_t)(_d + q * 512), 16, 0, 0);         \
    }

#define AONEHOT(LF)                                                            \
    {                                                                          \
        if (ps >= 0) Ash[ps] = 0;                                              \
        int l = (LF);                                                          \
        if (l < 32) {                                                          \
            int c = (ag << 2) + (l >> 3);                                      \
            ps = (am << 6) + ((c ^ (am & 7)) << 3) + (l & 7);                  \
            Ash[ps] = 0x3F80;                                                  \
        } else ps = -1;                                                        \
    }

#define BAR_A()  FENCE(); __builtin_amdgcn_s_barrier(); FENCE()
#define BAR_B()  asm volatile("s_waitcnt lgkmcnt(0)" ::: "memory");            \
                 __builtin_amdgcn_s_barrier(); FENCE()

#define MFMAPH(SLOT)                                                           \
    {                                                                          \
        const unsigned short* bb = Bsh + (SLOT) * 8192;                        \
        __builtin_amdgcn_s_setprio(1);                                         \
        _Pragma("unroll")                                                      \
        for (int ks = 0; ks < 2; ++ks) {                                       \
            const int c = (ks << 2) + kq;                                      \
            s16x8 af[4], bfr[4];                                               \
            _Pragma("unroll")                                                  \
            for (int mt = 0; mt < 4; ++mt) {                                   \
                int m = wm * 64 + mt * 16 + rr;                                \
                af[mt] = *(const s16x8*)&Ash[(m << 6) + ((c ^ (m & 7)) << 3)]; \
            }                                                                  \
            _Pragma("unroll")                                                  \
            for (int nt = 0; nt < 4; ++nt) {                                   \
                int n = wn * 64 + nt * 16 + rr;                                \
                bfr[nt] = *(const s16x8*)&bb[(n << 6) + ((c ^ (n & 7)) << 3)]; \
            }                                                                  \
            _Pragma("unroll")                                                  \
            for (int mt = 0; mt < 4; ++mt)                                     \
                _Pragma("unroll")                                              \
                for (int nt = 0; nt < 4; ++nt)                                 \
                    acc[mt][nt] = __builtin_amdgcn_mfma_f32_16x16x32_bf16(     \
                        af[mt], bfr[nt], acc[mt][nt], 0, 0, 0);                \
        }                                                                      \
        __builtin_amdgcn_s_setprio(0);                                         \
    }

    // prologue: fenced FIFO = [S(kbeg):4, L(kbeg):1, S(kbeg+1):4, L(kbeg+1):1]
    STAGE(kbeg, 0);
    FENCE();
    unsigned char lfa = lt[(size_t)(kbeg * 2 + ag) * BATCH + mbase + am];
    FENCE();
    STAGE(kbeg + 1, 1);
    FENCE();
    unsigned char lfb = lt[(size_t)((kbeg + 1) * 2 + ag) * BATCH + mbase + am];
    FENCE();

    // ring-3 slot rotation (66%3==0 -> same init both z)
    int sA = 0, sB = 1, sC = 2;

    // main loop: kb in [kbeg, kend1-2), unrolled x2 (named lfa/lfb; rule #20)
    for (int kb = kbeg; kb < kend1 - 2; kb += 2) {
        // ---- even body (kb): uses lfa, stages kb+2 -> sC, MFMA slot sA ----
        BAR_A();                                           // all MFMA(kb-1) done
        asm volatile("s_waitcnt vmcnt(5)" ::: "memory");   // S(kb)+L(kb) landed
        AONEHOT(lfa);
        FENCE();
        STAGE(kb + 2, sC);
        FENCE();
        lfa = lt[(size_t)((kb + 2) * 2 + ag) * BATCH + mbase + am];
        FENCE();
        BAR_B();                                           // A(kb)+S(kb) visible
        MFMAPH(sA);
        // ---- odd body (kb+1): uses lfb, stages kb+3 -> sA, MFMA slot sB ----
        BAR_A();
        asm volatile("s_waitcnt vmcnt(5)" ::: "memory");
        AONEHOT(lfb);
        FENCE();
        STAGE(kb + 3, sA);
        FENCE();
        lfb = lt[(size_t)((kb + 3) * 2 + ag) * BATCH + mbase + am];
        FENCE();
        BAR_B();
        MFMAPH(sB);
        // rotate: (sA,sB,sC) <- (sC,sA,sB)
        int tmp = sC; sC = sB; sB = sA; sA = tmp;
    }

    // peeled kb = kend1-2 (even) and kend1-1: no leaf prefetch; z=1 stages 128/129
    BAR_A();
    asm volatile("s_waitcnt vmcnt(5)" ::: "memory");       // S,L(kend1-2) landed
    AONEHOT(lfa);
    FENCE();
    if (zz) { STAGE(kend1, sC); FENCE(); }                 // B(128) -> sC
    BAR_B();
    MFMAPH(sA);

    BAR_A();
    if (zz) { asm volatile("s_waitcnt vmcnt(4)" ::: "memory"); }  // S,L(kend1-1)
    else    { asm volatile("s_waitcnt vmcnt(0)" ::: "memory"); }
    AONEHOT(lfb);
    FENCE();
    if (zz) { STAGE(kend1 + 1, sA); FENCE(); }             // B(129) -> sA
    BAR_B();
    MFMAPH(sB);

    // dense relu(x) tail kb 128..131 (z=1 only); slots: 128->sC,129->sA,
    // 130->sB,131->sC (ring-3; readers done before each re-stage)
    if (zz) {
#define DENSEA(KB)                                                             \
        {                                                                      \
            const float* xr = x + (size_t)(mbase + wv * 32) * IN_F             \
                                + ((KB) - 128) * 64 + lane;                    \
            const int cslot = (lane >> 3);                                     \
            _Pragma("unroll")                                                  \
            for (int m0 = 0; m0 < 32; ++m0) {                                  \
                int m = wv * 32 + m0;                                          \
                float v = xr[(size_t)m0 * IN_F];                               \
                Ash[(m << 6) + ((cslot ^ (m & 7)) << 3) + (lane & 7)] =        \
                    f2bf(fmaxf(v, 0.0f));                                      \
            }                                                                  \
        }
        BAR_A();
        asm volatile("s_waitcnt vmcnt(4)" ::: "memory");   // S(128) landed
        DENSEA(128);
        FENCE();
        STAGE(130, sB);
        FENCE();
        BAR_B();
        MFMAPH(sC);

        BAR_A();
        asm volatile("s_waitcnt vmcnt(4)" ::: "memory");   // S(129) landed
        DENSEA(129);
        FENCE();
        STAGE(131, sC);
        FENCE();
        BAR_B();
        MFMAPH(sA);

        BAR_A();
        asm volatile("s_waitcnt vmcnt(4)" ::: "memory");   // S(130) landed
        DENSEA(130);
        BAR_B();
        MFMAPH(sB);

        BAR_A();
        asm volatile("s_waitcnt vmcnt(0)" ::: "memory");   // S(131) landed
        DENSEA(131);
        BAR_B();
        MFMAPH(sC);
#undef DENSEA
    }

    // epilogue: C/D layout col=lane&15, row=(lane>>4)*4+reg; z-split -> atomicAdd
    const int rq = lane >> 4;
#pragma unroll
    for (int mt = 0; mt < 4; ++mt)
#pragma unroll
        for (int nt = 0; nt < 4; ++nt)
#pragma unroll
            for (int v = 0; v < 4; ++v) {
                int row = mbase + wm * 64 + mt * 16 + rq * 4 + v;
                int col = ntile * 128 + wn * 64 + nt * 16 + rr;
                atomicAdd(&out[(size_t)row * OUT_F + col], acc[mt][nt][v]);
            }
#undef STAGE
#undef AONEHOT
#undef BAR_A
#undef BAR_B
#undef MFMAPH
#undef FENCE
}

// ---------------- host ----------------
extern "C" void kernel_launch(void* const* d_in, const int* in_sizes, int n_in,
                              void* d_out, int out_size, void* d_ws, size_t ws_size,
                              hipStream_t stream) {
    (void)in_sizes; (void)n_in; (void)out_size; (void)ws_size;
    const float* x  = (const float*)d_in[0];   // [16384,256]
    const float* bw = (const float*)d_in[1];   // [256,256]
    const float* sw = (const float*)d_in[2];   // [256,256,31]
    const float* sc = (const float*)d_in[3];   // [256,256]
    float* out = (float*)d_out;

    char* ws = (char*)d_ws;
    unsigned short* Wb = (unsigned short*)ws;               // 4,325,376 B
    unsigned char*  lt = (unsigned char*)(ws + 4325376);    // 4,194,304 B  [i][b]
    float* pmn = (float*)(ws + 8519680);                    // 262,144 B
    float* pmx = (float*)(ws + 8781824);                    // 262,144 B

    prep1<<<768, 256, 0, stream>>>(x, bw, sw, sc, pmn, pmx, Wb, out);
    leaf2t<<<256, 256, 0, stream>>>(x, pmn, pmx, lt);
    gemm_kan<<<dim3(128, 2, 2), 256, 0, stream>>>(x, Wb, lt, out);
}